// Round 1
// baseline (3775.274 us; speedup 1.0000x reference)
//
#include <hip/hip_runtime.h>

#define NB 16
#define NL 100
#define NH 256
#define NG 1024
#define NOUT (16*101*101)

__device__ __forceinline__ float sigm(float x) {
    x = fminf(fmaxf(x, -30.f), 30.f);
    return 1.f / (1.f + __expf(-x));
}
__device__ __forceinline__ float tanh_(float x) {
    x = fminf(fmaxf(x, -15.f), 15.f);
    float t = __expf(2.f * x);
    return (t - 1.f) / (t + 1.f);
}

// ---------------- pack kernels ----------------

// whTp layout: [layer][dir][kb(64)][g(1024)][4]  (float4 per (kb,g))
__global__ __launch_bounds__(256) void pack_whT(const float* __restrict__ w_hh0,
                                                const float* __restrict__ w_hh,
                                                float* __restrict__ whTp) {
    int idx = blockIdx.x * 256 + threadIdx.x;          // over 8*64*1024
    if (idx >= 8 * 64 * 1024) return;
    int g  = idx & 1023;
    int kb = (idx >> 10) & 63;
    int ld = idx >> 16;                                 // l*2+d
    int l = ld >> 1, d = ld & 1;
    const float* src = (l == 0)
        ? (w_hh0 + ((size_t)d * 1024 + g) * 256 + kb * 4)
        : (w_hh + ((((size_t)(l - 1) * 2 + d) * 1024 + g) * 256) + kb * 4);
    float4 v = *(const float4*)src;
    ((float4*)whTp)[idx] = v;
}

// wi0p: [dir][g][160] zero-padded from K=150
__global__ __launch_bounds__(256) void pack_wi0(const float* __restrict__ w_ih0,
                                                float* __restrict__ wi0p) {
    int idx = blockIdx.x * 256 + threadIdx.x;          // over 2*1024*160
    if (idx >= 2 * 1024 * 160) return;
    int k = idx % 160;
    int g = (idx / 160) & 1023;
    int d = idx / (160 * 1024);
    float v = (k < 150) ? w_ih0[((size_t)d * 1024 + g) * 150 + k] : 0.f;
    wi0p[idx] = v;
}

// biasp: [layer][dir][1024] = b_ih + b_hh
__global__ __launch_bounds__(256) void pack_bias(const float* __restrict__ b_ih0,
                                                 const float* __restrict__ b_hh0,
                                                 const float* __restrict__ b_ih,
                                                 const float* __restrict__ b_hh,
                                                 float* __restrict__ biasp) {
    int idx = blockIdx.x * 256 + threadIdx.x;          // over 8*1024
    if (idx >= 8 * 1024) return;
    int g = idx & 1023;
    int ld = idx >> 10;
    int l = ld >> 1, d = ld & 1;
    float v;
    if (l == 0) v = b_ih0[d * 1024 + g] + b_hh0[d * 1024 + g];
    else {
        size_t o = ((size_t)(l - 1) * 2 + d) * 1024 + g;
        v = b_ih[o] + b_hh[o];
    }
    biasp[idx] = v;
}

// x0p: [B*L][160] = [word_embeds(100) | pos_emb[pos_idx](50) | 0(10)]
__global__ __launch_bounds__(256) void concat_x0(const float* __restrict__ we,
                                                 const int* __restrict__ pos_idx,
                                                 const float* __restrict__ pos_emb,
                                                 float* __restrict__ x0p) {
    int idx = blockIdx.x * 256 + threadIdx.x;          // over 1600*160
    if (idx >= 1600 * 160) return;
    int m = idx / 160, k = idx % 160;
    float v;
    if (k < 100) v = we[(size_t)m * 100 + k];
    else if (k < 150) v = pos_emb[(size_t)pos_idx[m] * 50 + (k - 100)];
    else v = 0.f;
    x0p[idx] = v;
}

__global__ __launch_bounds__(256) void zero_out(float* __restrict__ out) {
    int idx = blockIdx.x * 256 + threadIdx.x;
    if (idx < NOUT) out[idx] = 0.f;
}

// ---------------- generic fp32 GEMM: C[m, coff+n] = bias[n] + sum_k X[m,k]*W[n,k] ----
// grid: (M/64, N/64); block 256. M,N multiples of 64; K multiple of 16.
__global__ __launch_bounds__(256) void gemm_xwT(const float* __restrict__ X,
                                                const float* __restrict__ W,
                                                const float* __restrict__ bias,
                                                float* __restrict__ C,
                                                int K, int ldx, int ldw, int ldc, int coff) {
    __shared__ float As[16][68];
    __shared__ float Bs[16][68];
    const int t = threadIdx.x;
    const int m0 = blockIdx.x * 64, n0 = blockIdx.y * 64;
    const int lr = t >> 2, lc = (t & 3) * 4;
    const int tm = (t & 15) * 4, tn = (t >> 4) * 4;
    float acc[4][4] = {};
    for (int kc = 0; kc < K; kc += 16) {
        float4 av = *(const float4*)&X[(size_t)(m0 + lr) * ldx + kc + lc];
        float4 bv = *(const float4*)&W[(size_t)(n0 + lr) * ldw + kc + lc];
        __syncthreads();
        As[lc + 0][lr] = av.x; As[lc + 1][lr] = av.y; As[lc + 2][lr] = av.z; As[lc + 3][lr] = av.w;
        Bs[lc + 0][lr] = bv.x; Bs[lc + 1][lr] = bv.y; Bs[lc + 2][lr] = bv.z; Bs[lc + 3][lr] = bv.w;
        __syncthreads();
#pragma unroll
        for (int k = 0; k < 16; ++k) {
            float4 a = *(const float4*)&As[k][tm];
            float4 b = *(const float4*)&Bs[k][tn];
            acc[0][0] = fmaf(a.x, b.x, acc[0][0]);
            acc[0][1] = fmaf(a.x, b.y, acc[0][1]);
            acc[0][2] = fmaf(a.x, b.z, acc[0][2]);
            acc[0][3] = fmaf(a.x, b.w, acc[0][3]);
            acc[1][0] = fmaf(a.y, b.x, acc[1][0]);
            acc[1][1] = fmaf(a.y, b.y, acc[1][1]);
            acc[1][2] = fmaf(a.y, b.z, acc[1][2]);
            acc[1][3] = fmaf(a.y, b.w, acc[1][3]);
            acc[2][0] = fmaf(a.z, b.x, acc[2][0]);
            acc[2][1] = fmaf(a.z, b.y, acc[2][1]);
            acc[2][2] = fmaf(a.z, b.z, acc[2][2]);
            acc[2][3] = fmaf(a.z, b.w, acc[2][3]);
            acc[3][0] = fmaf(a.w, b.x, acc[3][0]);
            acc[3][1] = fmaf(a.w, b.y, acc[3][1]);
            acc[3][2] = fmaf(a.w, b.z, acc[3][2]);
            acc[3][3] = fmaf(a.w, b.w, acc[3][3]);
        }
    }
#pragma unroll
    for (int r = 0; r < 4; ++r) {
#pragma unroll
        for (int c = 0; c < 4; ++c) {
            float v = acc[r][c];
            if (bias) v += bias[n0 + tn + c];
            C[(size_t)(m0 + tm + r) * ldc + coff + n0 + tn + c] = v;
        }
    }
}

// ---------------- LSTM recurrence: one block per (dir, batch) ----------------
// gx: [2][B*L][1024] (already has x@w_ih^T + b_ih + b_hh)
// whTp: this layer, [dir][kb][g][4]
// xout: [B*L][512], h written at [.., d*256+u]
__global__ __launch_bounds__(1024) void lstm_layer(const float* __restrict__ gx,
                                                   const float* __restrict__ whTp,
                                                   float* __restrict__ xout) {
    const int d = blockIdx.x >> 4;
    const int b = blockIdx.x & 15;
    const int g = threadIdx.x;
    __shared__ float hs[256];
    __shared__ float cs[256];
    __shared__ float gates[1024];
    if (g < 256) { hs[g] = 0.f; cs[g] = 0.f; }
    __syncthreads();
    const float4* wp = (const float4*)whTp + (size_t)d * 64 * 1024 + g;
    const float* gxb = gx + ((size_t)d * 1600 + b * 100) * 1024;
    for (int s = 0; s < NL; ++s) {
        const int tt = d ? (NL - 1 - s) : s;
        float acc = gxb[(size_t)tt * 1024 + g];
        const float4* hp = (const float4*)hs;
#pragma unroll 8
        for (int kb = 0; kb < 64; ++kb) {
            float4 w = wp[(size_t)kb * 1024];
            float4 hv = hp[kb];
            acc = fmaf(w.x, hv.x, acc);
            acc = fmaf(w.y, hv.y, acc);
            acc = fmaf(w.z, hv.z, acc);
            acc = fmaf(w.w, hv.w, acc);
        }
        gates[g] = acc;
        __syncthreads();
        if (g < 256) {
            float ig = sigm(gates[g]);
            float fg = sigm(gates[256 + g]);
            float gg = tanh_(gates[512 + g]);
            float og = sigm(gates[768 + g]);
            float cn = fmaf(fg, cs[g], ig * gg);
            cs[g] = cn;
            float hn = og * tanh_(cn);
            hs[g] = hn;
            xout[((size_t)b * NL + tt) * 512 + d * 256 + g] = hn;
        }
        __syncthreads();
    }
}

// ---------------- fused scorer ----------------
// hfr: [B*100][1024]: cols [0:512) = hf[b][i], cols [512:1024) = hr[b][j-1+1]
// block computes 8 i x 16 j pairs for batch b over all 128 channels, K=512
__global__ __launch_bounds__(256) void scorer_kernel(const float* __restrict__ hfr,
                                                     const float* __restrict__ W2,
                                                     const float* __restrict__ b1,
                                                     const float* __restrict__ b2,
                                                     const float* __restrict__ W3,
                                                     const float* __restrict__ b3,
                                                     const int* __restrict__ sen_lens,
                                                     float* __restrict__ out) {
    const int t = threadIdx.x;
    const int b = blockIdx.z;
    const int i0 = blockIdx.x * 8;
    const int j0 = blockIdx.y * 16;

    __shared__ float h1s[32][130];
    __shared__ float w2s[32][130];
    __shared__ float hfs[8][33];
    __shared__ float hrs[16][33];
    __shared__ float b1s[32];
    __shared__ float part[128][17];

    const int pg = t & 15;
    const int ng = t >> 4;
    const int wn = t >> 1;
    const int wk = (t & 1) * 16;
    float acc[8][8] = {};

    for (int kc = 0; kc < 512; kc += 32) {
        float4 wv0 = *(const float4*)&W2[(size_t)wn * 512 + kc + wk + 0];
        float4 wv1 = *(const float4*)&W2[(size_t)wn * 512 + kc + wk + 4];
        float4 wv2 = *(const float4*)&W2[(size_t)wn * 512 + kc + wk + 8];
        float4 wv3 = *(const float4*)&W2[(size_t)wn * 512 + kc + wk + 12];
        float4 sv = make_float4(0.f, 0.f, 0.f, 0.f);
        if (t < 64) {
            int row = t >> 3, c = (t & 7) * 4;
            int i = i0 + row;
            if (i < 100) sv = *(const float4*)&hfr[((size_t)b * 100 + i) * 1024 + kc + c];
        } else if (t < 192) {
            int idx = t - 64, row = idx >> 3, c = (idx & 7) * 4;
            int j = j0 + row;
            if (j >= 1 && j <= 100)
                sv = *(const float4*)&hfr[((size_t)b * 100 + j - 1) * 1024 + 512 + kc + c];
        } else if (t < 200) {
            sv = *(const float4*)&b1[kc + (t - 192) * 4];
        }
        __syncthreads();   // previous chunk fully consumed
        if (t < 64) {
            int row = t >> 3, c = (t & 7) * 4;
            hfs[row][c + 0] = sv.x; hfs[row][c + 1] = sv.y; hfs[row][c + 2] = sv.z; hfs[row][c + 3] = sv.w;
        } else if (t < 192) {
            int idx = t - 64, row = idx >> 3, c = (idx & 7) * 4;
            hrs[row][c + 0] = sv.x; hrs[row][c + 1] = sv.y; hrs[row][c + 2] = sv.z; hrs[row][c + 3] = sv.w;
        } else if (t < 200) {
            int c = (t - 192) * 4;
            b1s[c + 0] = sv.x; b1s[c + 1] = sv.y; b1s[c + 2] = sv.z; b1s[c + 3] = sv.w;
        }
        w2s[wk + 0][wn] = wv0.x;  w2s[wk + 1][wn] = wv0.y;  w2s[wk + 2][wn] = wv0.z;  w2s[wk + 3][wn] = wv0.w;
        w2s[wk + 4][wn] = wv1.x;  w2s[wk + 5][wn] = wv1.y;  w2s[wk + 6][wn] = wv1.z;  w2s[wk + 7][wn] = wv1.w;
        w2s[wk + 8][wn] = wv2.x;  w2s[wk + 9][wn] = wv2.y;  w2s[wk + 10][wn] = wv2.z; w2s[wk + 11][wn] = wv2.w;
        w2s[wk + 12][wn] = wv3.x; w2s[wk + 13][wn] = wv3.y; w2s[wk + 14][wn] = wv3.z; w2s[wk + 15][wn] = wv3.w;
        __syncthreads();   // staging ready
        {
            int p = t & 127, kh = (t >> 7) * 16;
            int pi = p >> 4, pj = p & 15;
#pragma unroll
            for (int kk = 0; kk < 16; ++kk) {
                int k = kh + kk;
                h1s[k][p] = fmaxf(hfs[pi][k] + hrs[pj][k] + b1s[k], 0.f);
            }
        }
        __syncthreads();   // h1 tile ready
#pragma unroll 4
        for (int k = 0; k < 32; ++k) {
            float4 a0 = *(const float4*)&h1s[k][pg * 8];
            float4 a1 = *(const float4*)&h1s[k][pg * 8 + 4];
            float4 c0 = *(const float4*)&w2s[k][ng * 8];
            float4 c1 = *(const float4*)&w2s[k][ng * 8 + 4];
            float av[8] = {a0.x, a0.y, a0.z, a0.w, a1.x, a1.y, a1.z, a1.w};
            float cv[8] = {c0.x, c0.y, c0.z, c0.w, c1.x, c1.y, c1.z, c1.w};
#pragma unroll
            for (int r = 0; r < 8; ++r)
#pragma unroll
                for (int c = 0; c < 8; ++c)
                    acc[r][c] = fmaf(av[r], cv[c], acc[r][c]);
        }
    }
    // epilogue: h2 = relu(acc + b2), sc = h2 . W3 + b3, mask, write
    float w3r[8], b2r[8];
#pragma unroll
    for (int c = 0; c < 8; ++c) {
        w3r[c] = W3[ng * 8 + c];
        b2r[c] = b2[ng * 8 + c];
    }
#pragma unroll
    for (int r = 0; r < 8; ++r) {
        float sp = 0.f;
#pragma unroll
        for (int c = 0; c < 8; ++c)
            sp += fmaxf(acc[r][c] + b2r[c], 0.f) * w3r[c];
        part[pg * 8 + r][ng] = sp;
    }
    __syncthreads();
    if (t < 128) {
        float s = 0.f;
#pragma unroll
        for (int g2 = 0; g2 < 16; ++g2) s += part[t][g2];
        int i = i0 + (t >> 4), j = j0 + (t & 15);
        if (i < 100 && j < 101) {
            float v = s + b3[0];
            int sl = sen_lens[b];
            if (!((i < sl) && (j <= sl)) || (i == 0 && j == 0)) v = 0.f;
            out[((size_t)b * 101 + i) * 101 + j] = v;
        }
    }
}

// ---------------- launcher ----------------
extern "C" void kernel_launch(void* const* d_in, const int* in_sizes, int n_in,
                              void* d_out, int out_size, void* d_ws, size_t ws_size,
                              hipStream_t stream) {
    const float* we       = (const float*)d_in[0];
    const int*   pos_idx  = (const int*)d_in[1];
    const int*   sen_lens = (const int*)d_in[2];
    const float* pos_emb  = (const float*)d_in[3];
    const float* w_ih0    = (const float*)d_in[4];
    const float* w_hh0    = (const float*)d_in[5];
    const float* b_ih0    = (const float*)d_in[6];
    const float* b_hh0    = (const float*)d_in[7];
    const float* w_ih     = (const float*)d_in[8];
    const float* w_hh     = (const float*)d_in[9];
    const float* b_ih     = (const float*)d_in[10];
    const float* b_hh     = (const float*)d_in[11];
    const float* W1       = (const float*)d_in[12];
    const float* b1       = (const float*)d_in[13];
    const float* W2       = (const float*)d_in[14];
    const float* b2       = (const float*)d_in[15];
    const float* W3       = (const float*)d_in[16];
    const float* b3       = (const float*)d_in[17];
    float* out = (float*)d_out;

    float* ws    = (float*)d_ws;
    float* x0p   = ws;                      // 256000
    float* gx    = x0p + 256000;            // 3276800
    float* xA    = gx + 3276800;            // 819200
    float* xB    = xA + 819200;             // 819200
    float* hfr   = xB + 819200;             // 1638400
    float* whTp  = hfr + 1638400;           // 2097152
    float* wi0p  = whTp + 2097152;          // 327680
    float* biasp = wi0p + 327680;           // 8192

    pack_whT<<<2048, 256, 0, stream>>>(w_hh0, w_hh, whTp);
    pack_wi0<<<1280, 256, 0, stream>>>(w_ih0, wi0p);
    pack_bias<<<32, 256, 0, stream>>>(b_ih0, b_hh0, b_ih, b_hh, biasp);
    concat_x0<<<1000, 256, 0, stream>>>(we, pos_idx, pos_emb, x0p);

    // layer 0: K=160 (padded)
    for (int d = 0; d < 2; ++d)
        gemm_xwT<<<dim3(25, 16), 256, 0, stream>>>(
            x0p, wi0p + (size_t)d * 1024 * 160, biasp + d * 1024,
            gx + (size_t)d * 1600 * 1024, 160, 160, 160, 1024, 0);
    lstm_layer<<<32, 1024, 0, stream>>>(gx, whTp, xA);

    const float* xin = xA;
    float* xo = xB;
    for (int l = 1; l < 4; ++l) {
        for (int d = 0; d < 2; ++d)
            gemm_xwT<<<dim3(25, 16), 256, 0, stream>>>(
                xin, w_ih + (((size_t)(l - 1) * 2 + d) * 1024) * 512,
                biasp + (l * 2 + d) * 1024,
                gx + (size_t)d * 1600 * 1024, 512, 512, 512, 1024, 0);
        lstm_layer<<<32, 1024, 0, stream>>>(gx, whTp + (size_t)l * 524288, xo);
        float* tmp = (float*)xin; xin = xo; xo = tmp;
    }
    const float* lstm_out = xin;   // = xB after 4 layers

    // hf -> cols [0:512), hr(j-1) -> cols [512:1024)
    gemm_xwT<<<dim3(25, 8), 256, 0, stream>>>(lstm_out, W1, nullptr, hfr,
                                              512, 512, 1024, 1024, 0);
    gemm_xwT<<<dim3(25, 8), 256, 0, stream>>>(lstm_out, W1 + 512, nullptr, hfr,
                                              512, 512, 1024, 1024, 512);

    zero_out<<<(NOUT + 255) / 256, 256, 0, stream>>>(out);
    scorer_kernel<<<dim3(13, 7, 16), 256, 0, stream>>>(hfr, W2, b1, b2, W3, b3,
                                                       sen_lens, out);
}